// Round 8
// baseline (23902.629 us; speedup 1.0000x reference)
//
#include <hip/hip_runtime.h>

#define T_STEPS 65536
#define NIN 99
#define HID 64
#define G4 256   // 4*HID gates
#define TS 128   // timesteps per block in the projection kernel

typedef __attribute__((ext_vector_type(2))) float f32x2;

__device__ __forceinline__ float frcp(float x) { return __builtin_amdgcn_rcpf(x); }
__device__ __forceinline__ float fexp(float x) { return __expf(x); }
__device__ __forceinline__ float sigmoid_f(float x) { return frcp(1.0f + fexp(-x)); }
__device__ __forceinline__ float tanh_f(float x) {
    float ax = fabsf(x);
    float e  = fexp(2.0f * ax);                 // inf for large ax fine: rcp(inf)=0
    float r  = 1.0f - 2.0f * frcp(e + 1.0f);
    return copysignf(r, x);
}
// wave-uniform broadcast of lane `lane`'s value via readlane (VALU->SGPR)
__device__ __forceinline__ float bcast(float v, int lane) {
    return __int_as_float(__builtin_amdgcn_readlane(__float_as_int(v), lane));
}

// LDS-only barrier: waits ds ops (lgkmcnt) but leaves global loads (vmcnt)
// in flight across the barrier (R7: this removed the vmcnt(0) prefetch drain).
#define BAR_LGKM() asm volatile("s_waitcnt lgkmcnt(0)\n\ts_barrier" ::: "memory")

// ---------------- Kernel 1: xz2[t][unit][4] = gates (i,f,g,o) of unit ----------------
__global__ __launch_bounds__(256, 1) void xz_kernel(
    const float* __restrict__ x, const float* __restrict__ W_ih,
    const float* __restrict__ b_ih, const float* __restrict__ b_hh,
    float* __restrict__ xz2) {
    __shared__ __align__(16) float xs[TS * 100];   // padded rows: 400 B stride
    const int g  = threadIdx.x;                    // gate row 0..255
    const int t0 = blockIdx.x * TS;
    const int unit = g & 63, d = g >> 6;           // transposed write position

    for (int i = g; i < TS * NIN; i += 256) {
        int tl = i / NIN;
        int j  = i - tl * NIN;
        xs[tl * 100 + j] = x[(size_t)t0 * NIN + i];
    }

    float w[NIN];
#pragma unroll
    for (int j = 0; j < NIN; ++j) w[j] = W_ih[g * NIN + j];
    const float bias = b_ih[g] + b_hh[g];
    __syncthreads();

    for (int tl = 0; tl < TS; ++tl) {
        const float* xr = &xs[tl * 100];
        float a0 = bias, a1 = 0.f, a2 = 0.f, a3 = 0.f;
#pragma unroll
        for (int j4 = 0; j4 < 24; ++j4) {
            float4 xv = *(const float4*)(xr + 4 * j4);
            a0 = fmaf(w[4 * j4 + 0], xv.x, a0);
            a1 = fmaf(w[4 * j4 + 1], xv.y, a1);
            a2 = fmaf(w[4 * j4 + 2], xv.z, a2);
            a3 = fmaf(w[4 * j4 + 3], xv.w, a3);
        }
        a0 = fmaf(w[96], xr[96], a0);
        a1 = fmaf(w[97], xr[97], a1);
        a2 = fmaf(w[98], xr[98], a2);
        xz2[(size_t)(t0 + tl) * G4 + unit * 4 + d] = (a0 + a1) + (a2 + a3);
    }
}

// ---------------- Kernel 2: split-K LSTM, unit-major, pk_fma, rolling z ----------------
// Phase 1: thread (wv,l) computes the 4 gates (i,f,g,o) OF UNIT l over k-chunk
//   [16wv,16wv+16): 16 readlane + 32 v_pk_fma_f32; writes one float4 partial.
// BAR_LGKM (z prefetch stays in flight).
// Phase 2 (replicated): 3 ds_read_b128 of the other chunks' partials, reduce
//   (+ own z, loaded identically by all waves), activate, update own c,h.
// z prefetch: rolling 4-deep float4 buffer (16 VGPRs) -> low pressure so the
// 64 weight floats stay in ARCH VGPRs (R7: z dbuf pushed them into AGPRs,
// costing ~64 v_accvgpr_read per step).
__global__ __launch_bounds__(256, 1) __attribute__((amdgpu_waves_per_eu(1)))
void lstm_kernel(
    const float* __restrict__ xz2, const float* __restrict__ W_hh,
    const float* __restrict__ W1, const float* __restrict__ W2,
    const float* __restrict__ b2, float* __restrict__ out) {
    __shared__ __align__(16) float4 pbuf[2][4][HID];   // [parity][k-chunk][unit]
    __shared__ float hfin[HID];
    __shared__ float hbuf[32];
    const int tid = threadIdx.x;
    const int l   = tid & 63;
    const int wv  = tid >> 6;
    const int sb  = __builtin_amdgcn_readfirstlane(16 * wv);   // k-chunk base

    // weights: rows l (i), 64+l (f), 128+l (g), 192+l (o); cols [sb, sb+16)
    const float* Wb = W_hh + l * HID + sb;
    float4 wi0 = *(const float4*)(Wb +     0), wi1 = *(const float4*)(Wb +     4),
           wi2 = *(const float4*)(Wb +     8), wi3 = *(const float4*)(Wb +    12);
    float4 wf0 = *(const float4*)(Wb +  4096), wf1 = *(const float4*)(Wb +  4100),
           wf2 = *(const float4*)(Wb +  4104), wf3 = *(const float4*)(Wb +  4108);
    float4 wg0 = *(const float4*)(Wb +  8192), wg1 = *(const float4*)(Wb +  8196),
           wg2 = *(const float4*)(Wb +  8200), wg3 = *(const float4*)(Wb +  8204);
    float4 wo0 = *(const float4*)(Wb + 12288), wo1 = *(const float4*)(Wb + 12292),
           wo2 = *(const float4*)(Wb + 12296), wo3 = *(const float4*)(Wb + 12300);

#define PIN4(v) asm volatile("" : "+v"(v.x), "+v"(v.y), "+v"(v.z), "+v"(v.w))
    PIN4(wi0); PIN4(wi1); PIN4(wi2); PIN4(wi3);
    PIN4(wf0); PIN4(wf1); PIN4(wf2); PIN4(wf3);
    PIN4(wg0); PIN4(wg1); PIN4(wg2); PIN4(wg3);
    PIN4(wo0); PIN4(wo1); PIN4(wo2); PIN4(wo3);
#undef PIN4

    float h = 0.0f, c = 0.0f;       // lane l of every wave: h[l], c[l]

    // rolling 4-deep z prefetch; ALL waves load (L1-shared, keeps waves balanced)
    const float* zi = xz2 + 4 * l;
    float4 zb0 = *(const float4*)(zi + 0 * G4);
    float4 zb1 = *(const float4*)(zi + 1 * G4);
    float4 zb2 = *(const float4*)(zi + 2 * G4);
    float4 zb3 = *(const float4*)(zi + 3 * G4);

#define F2XY(v) ((f32x2){v.x, v.y})
#define F2ZW(v) ((f32x2){v.z, v.w})
#define PAIR(KOFF, HI, WI2, WF2, WG2, WO2)                                      \
    {   f32x2 h2;                                                               \
        h2.x = bcast(h, sb + (KOFF));                                           \
        h2.y = bcast(h, sb + (KOFF) + 1);                                       \
        (void)(HI);                                                             \
        ai = __builtin_elementwise_fma(WI2, h2, ai);                            \
        af = __builtin_elementwise_fma(WF2, h2, af);                            \
        ag = __builtin_elementwise_fma(WG2, h2, ag);                            \
        ao = __builtin_elementwise_fma(WO2, h2, ao); }

#define STEP(U, PAR, ZB)                                                        \
    {   float4 zv = ZB;                                                         \
        /* issue next prefetch for this slot (stays in flight across barrier) */\
        {   int sn = tb + (U) + 4; sn = sn < T_STEPS ? sn : T_STEPS - 1;        \
            ZB = *(const float4*)(zi + (size_t)sn * G4); }                      \
        f32x2 ai = {0.f, 0.f}, af = {0.f, 0.f}, ag = {0.f, 0.f}, ao = {0.f, 0.f};\
        PAIR(0,  0, F2XY(wi0), F2XY(wf0), F2XY(wg0), F2XY(wo0))                 \
        PAIR(2,  0, F2ZW(wi0), F2ZW(wf0), F2ZW(wg0), F2ZW(wo0))                 \
        PAIR(4,  0, F2XY(wi1), F2XY(wf1), F2XY(wg1), F2XY(wo1))                 \
        PAIR(6,  0, F2ZW(wi1), F2ZW(wf1), F2ZW(wg1), F2ZW(wo1))                 \
        PAIR(8,  0, F2XY(wi2), F2XY(wf2), F2XY(wg2), F2XY(wo2))                 \
        PAIR(10, 0, F2ZW(wi2), F2ZW(wf2), F2ZW(wg2), F2ZW(wo2))                 \
        PAIR(12, 0, F2XY(wi3), F2XY(wf3), F2XY(wg3), F2XY(wo3))                 \
        PAIR(14, 0, F2ZW(wi3), F2ZW(wf3), F2ZW(wg3), F2ZW(wo3))                 \
        pbuf[PAR][wv][l] = make_float4(ai.x + ai.y, af.x + af.y,                \
                                       ag.x + ag.y, ao.x + ao.y);               \
        BAR_LGKM();                                                             \
        float4 r0 = pbuf[PAR][(wv + 1) & 3][l];                                 \
        float4 r1 = pbuf[PAR][(wv + 2) & 3][l];                                 \
        float4 r2 = pbuf[PAR][(wv + 3) & 3][l];                                 \
        float si = (zv.x + (ai.x + ai.y)) + ((r0.x + r1.x) + r2.x);             \
        float sf = (zv.y + (af.x + af.y)) + ((r0.y + r1.y) + r2.y);             \
        float sg = (zv.z + (ag.x + ag.y)) + ((r0.z + r1.z) + r2.z);             \
        float so = (zv.w + (ao.x + ao.y)) + ((r0.w + r1.w) + r2.w);             \
        float ig = sigmoid_f(si);                                               \
        float fg = sigmoid_f(sf);                                               \
        float gg = tanh_f(sg);                                                  \
        float og = sigmoid_f(so);                                               \
        c = fmaf(fg, c, ig * gg);                                               \
        h = og * tanh_f(c); }

    for (int tb = 0; tb < T_STEPS; tb += 4) {
        STEP(0, 0, zb0)
        STEP(1, 1, zb1)
        STEP(2, 0, zb2)
        STEP(3, 1, zb3)
    }
#undef STEP
#undef PAIR
#undef F2XY
#undef F2ZW

    // head: out = W2 @ relu(W1 @ relu(h_T)) + b2
    if (tid < HID) hfin[tid] = h;
    __syncthreads();
    if (tid < 32) {
        float s = 0.0f;
#pragma unroll
        for (int j = 0; j < HID; ++j) s += W1[tid * HID + j] * fmaxf(hfin[j], 0.0f);
        hbuf[tid] = fmaxf(s, 0.0f);
    }
    __syncthreads();
    if (tid < 3) {
        float s = b2[tid];
#pragma unroll
        for (int j = 0; j < 32; ++j) s += W2[tid * 32 + j] * hbuf[j];
        out[tid] = s;
    }
}

extern "C" void kernel_launch(void* const* d_in, const int* in_sizes, int n_in,
                              void* d_out, int out_size, void* d_ws, size_t ws_size,
                              hipStream_t stream) {
    const float* x   = (const float*)d_in[0];
    const float* Wih = (const float*)d_in[1];
    const float* Whh = (const float*)d_in[2];
    const float* bih = (const float*)d_in[3];
    const float* bhh = (const float*)d_in[4];
    const float* W1  = (const float*)d_in[5];
    const float* W2  = (const float*)d_in[6];
    const float* b2  = (const float*)d_in[7];
    float* out = (float*)d_out;
    float* xz2 = (float*)d_ws;   // T_STEPS * 256 floats = 64 MB (transposed layout)

    xz_kernel<<<T_STEPS / TS, 256, 0, stream>>>(x, Wih, bih, bhh, xz2);
    lstm_kernel<<<1, 256, 0, stream>>>(xz2, Whh, W1, W2, b2, out);
}